// Round 22
// baseline (436.013 us; speedup 1.0000x reference)
//
#include <hip/hip_runtime.h>
#include <cstdint>

#define B_   32
#define CIN  256
#define COUT 256
#define H_   56
#define W_   56
#define HP   58          // padded spatial dim (pad=1 each side)
#define HW   (H_ * W_)   // 3136
#define NTILE 1792       // B*14*2*2 conv tiles

typedef int   v4i  __attribute__((ext_vector_type(4)));
typedef int   v8i  __attribute__((ext_vector_type(8)));
typedef float v16f __attribute__((ext_vector_type(16)));

// ==================================================================
// XNOR conv via MX-fp4 MFMA: a,w in {+1,-1} as fp4 e2m1 (+1=0x2,
// -1=0xA), zero-pad = 0x0 (exact). Unity scales (0x7F7F7F7F).
// Products +-1, |sums| <= 2304: exact in fp32. absmax 0 (r14-r21).
// ==================================================================

// ---- fused pack v3 (r21-verified) + counter reset block ----
__global__ __launch_bounds__(256, 8) void pack_kernel(
    const float* __restrict__ x, const float* __restrict__ alpha,
    const float* __restrict__ wt, char* __restrict__ A4,
    v4i* __restrict__ Wf, uint32_t* __restrict__ cnt) {
  __shared__ alignas(16) char sm[4096];
  const int bidx = blockIdx.x;
  const int tid = threadIdx.x;
  if (bidx < 3136) {
    // ---------------- pack_a4 main (interior pixels) ----------------
    const int b = bidx / 98;
    const int chunk = bidx - b * 98;       // 98 chunks of 32 px = 3136
    const int pixbase = chunk * 32;
    const int pxl = tid & 31;
    const int g = tid >> 5;                // ci granule 0..7
    const int pix = pixbase + pxl;

    const float* xp = x + ((size_t)(b * CIN + g * 32) * HW + pix);
    uint32_t wd[4];
    #pragma unroll
    for (int u = 0; u < 4; ++u) {          // 8 channels -> one u32
      uint32_t word = 0;
      #pragma unroll
      for (int n = 0; n < 8; ++n) {
        int c = u * 8 + n;
        float v = xp[(size_t)c * HW];
        word |= ((v > alpha[g * 32 + c]) ? 0x2u : 0xAu) << (n * 4);
      }
      wd[u] = word;
    }
    *(uint4*)(sm + pxl * 128 + ((g ^ (pxl & 7)) << 4)) = *(uint4*)wd;
    __syncthreads();
    const int px2 = tid >> 3;              // 0..31
    const int slot = tid & 7;
    uint4 v = *(const uint4*)(sm + px2 * 128 + ((slot ^ (px2 & 7)) << 4));
    const int gpix = pixbase + px2;
    const int h = gpix / 56;
    const int w = gpix - h * 56;
    char* dst = A4 + ((size_t)(b * HP + h + 1) * HP + (w + 1)) * 128 + slot * 16;
    *(uint4*)dst = v;
  } else if (bidx < 3368) {
    // ---------------- border zeroing (r20-verified) ----------------
    int t = (bidx - 3136) * 256 + tid;     // 0..59391
    if (t >= 32 * 1856) return;
    int b = t / 1856;
    int r = t - b * 1856;
    int hh, ww, idx;
    if (r < 928) {
      hh = (r < 464) ? 0 : (HP - 1);
      idx = (r < 464) ? r : r - 464;       // r % 464 (explicit)
      ww = idx >> 3;
    } else {
      int r2 = r - 928;
      ww = (r2 < 464) ? 0 : (HP - 1);
      idx = (r2 < 464) ? r2 : r2 - 464;    // r2 % 464 (explicit)
      hh = idx >> 3;
    }
    int g = idx & 7;
    char* dst = A4 + ((size_t)(b * HP + hh) * HP + ww) * 128 + g * 16;
    *(uint4*)dst = make_uint4(0u, 0u, 0u, 0u);
  } else if (bidx < 3440) {
    // ---------------- pack_w4 (r20-verified) ----------------
    int id = (bidx - 3368) * 256 + tid;    // 18432 total
    int lane = id & 63;
    int ng = (id >> 6) & 7;
    int kc = (id >> 9) & 3;
    int tap = id >> 11;
    if (tap >= 9) return;
    int kh = tap / 3, kw = tap - kh * 3;
    int co = ng * 32 + (lane & 31);
    int cib = kc * 64 + (lane >> 5) * 32;
    uint32_t wd[4];
    #pragma unroll
    for (int u = 0; u < 4; ++u) {
      uint32_t word = 0;
      #pragma unroll
      for (int n = 0; n < 8; ++n) {
        int ci = cib + u * 8 + n;
        float v = wt[((size_t)(co * CIN + ci) * 3 + kh) * 3 + kw];
        word |= ((v > 0.0f) ? 0x2u : 0xAu) << (n * 4);
      }
      wd[u] = word;
    }
    Wf[id] = *(v4i*)wd;
  } else {
    // ---------------- tile-counter reset (each launch) ----------------
    if (tid == 0) *cnt = 0u;
  }
}

// undef-high v8i: fp4 operands (cbsz/blgp=4) read only v[0:3]; leaving
// v[4:7] undef avoids zero-fill movs and ~32 live VGPRs (r15 lesson).
static __device__ __forceinline__ v8i up8(v4i x) {
  return __builtin_shufflevector(x, x, 0, 1, 2, 3, -1, -1, -1, -1);
}

// ---- conv_mfma v15: r21 tile body, PERSISTENT blocks + dynamic grab ----
// Grid = 1024 (exactly 4 blocks/CU resident). Each block loops
// t = atomicAdd(cnt) over 1792 tiles -> no 4+3 generation tails
// (r12-i8 counters: time-avg occupancy 2.65/4 = ~30% pacing loss).
// Tile body (decode/fill/batches/epilogue) identical to r21-verified.
__global__ __launch_bounds__(256, 4) void conv_mfma_kernel(
    const char* __restrict__ A4, const v4i* __restrict__ Wf,
    uint32_t* __restrict__ cnt, float* __restrict__ out) {
  __shared__ alignas(16) char lds[26112];   // [gr8][rr6][ww34] x 16B
  __shared__ int s_tile;
  const int tid = threadIdx.x;
  const int lane = tid & 63;
  const int l31 = lane & 31;
  const int hi  = lane >> 5;
  const int wn  = tid >> 6;

  // thread-constant pieces
  const char* abase = lds + hi * 3264 + l31 * 16;

  for (;;) {
    if (tid == 0) s_tile = (int)atomicAdd(cnt, 1u);
    __syncthreads();                 // broadcast tile; slab safe to refill
    const int t = s_tile;
    if (t >= NTILE) break;

    // t -> XCD-chunked bijective swizzle (1792 = 8*224)
    const int wg  = (t & 7) * 224 + (t >> 3);
    const int coh = wg & 1;
    const int owc = (wg >> 1) & 1;
    const int rest = wg >> 2;
    const int ohq = rest % 14;
    const int b   = rest / 14;
    const int oh0 = ohq * 4;
    const int owbase = owc * 32;

    // ---- fill slab: linear i = (gr*6+rr)*34 + wwl ----
    {
      const char* srcT = A4 + ((size_t)(b * HP + oh0) * HP + owbase) * 128;
      for (int i = tid; i < 1632; i += 256) {
        int gr  = i / 204;             // ci granule 0..7 (kc*2+hi)
        int rem = i - gr * 204;
        int rr  = rem / 34;
        int wwl = rem - rr * 34;
        uint4 v = make_uint4(0u, 0u, 0u, 0u);
        if (owbase + wwl < HP)
          v = *(const uint4*)(srcT + ((size_t)rr * HP + wwl) * 128 + gr * 16);
        *(uint4*)(lds + i * 16) = v;
      }
    }
    __syncthreads();

    v16f acc[4];
    #pragma unroll
    for (int m = 0; m < 4; ++m)
      #pragma unroll
      for (int e = 0; e < 16; ++e) acc[m][e] = 0.0f;

    const v4i* wb = Wf + (coh * 4 + wn) * 64 + lane;  // ng = coh*4+wn

    #pragma unroll
    for (int kc = 0; kc < 4; ++kc) {
      #pragma unroll
      for (int kw = 0; kw < 3; ++kw) {
        v4i af[6];
        #pragma unroll
        for (int rr = 0; rr < 6; ++rr)
          af[rr] = *(const v4i*)(abase + kc * 6528 + rr * 544 + kw * 16);
        v4i bf[3];
        #pragma unroll
        for (int kh = 0; kh < 3; ++kh)
          bf[kh] = wb[((kh * 3 + kw) * 4 + kc) * 512];
        #pragma unroll
        for (int kh = 0; kh < 3; ++kh) {
          v8i b8 = up8(bf[kh]);
          #pragma unroll
          for (int ohl = 0; ohl < 4; ++ohl) {
            acc[ohl] = __builtin_amdgcn_mfma_scale_f32_32x32x64_f8f6f4(
                up8(af[ohl + kh]), b8, acc[ohl], 4, 4,   // cbsz/blgp=4 (fp4)
                0, 0x7F7F7F7F, 0, 0x7F7F7F7F);           // unity scales
          }
        }
      }
    }

    // ---- epilogue: per-wave transpose via dead slab, row stores ----
    __syncthreads();                 // slab dead for all waves
    char* scr = lds + wn * 4608;     // [co 32] stride 144B x 32 floats
    const int co0 = (coh * 4 + wn) * 32;

    #pragma unroll
    for (int ohl = 0; ohl < 4; ++ohl) {
      #pragma unroll
      for (int q = 0; q < 4; ++q) {
        float4 f;
        f.x = acc[ohl][q * 4 + 0];
        f.y = acc[ohl][q * 4 + 1];
        f.z = acc[ohl][q * 4 + 2];
        f.w = acc[ohl][q * 4 + 3];
        // m = q*8 + hi*4 + j -> byte q*32 + hi*16
        *(float4*)(scr + l31 * 144 + q * 32 + hi * 16) = f;
      }
      asm volatile("s_waitcnt lgkmcnt(0)" ::: "memory");
      __builtin_amdgcn_sched_barrier(0);
      #pragma unroll
      for (int tt = 0; tt < 4; ++tt) {
        int idx = tt * 64 + lane;    // 0..255 = co_l*8 + s
        int co_l = idx >> 3;
        int s = idx & 7;
        int ow = owbase + s * 4;
        if (ow + 3 < W_) {           // owc=1 drops s>=6 (garbage cols)
          float4 v = *(const float4*)(scr + co_l * 144 + s * 16);
          float* op = out + ((size_t)(b * COUT + co0 + co_l) * H_ + oh0 + ohl) * W_ + ow;
          *(float4*)op = v;
        }
      }
      asm volatile("s_waitcnt lgkmcnt(0)" ::: "memory");
      __builtin_amdgcn_sched_barrier(0);
    }
  }
}

// ==================================================================
extern "C" void kernel_launch(void* const* d_in, const int* in_sizes, int n_in,
                              void* d_out, int out_size, void* d_ws, size_t ws_size,
                              hipStream_t stream) {
  const float* x     = (const float*)d_in[0];
  const float* alpha = (const float*)d_in[1];
  const float* wt    = (const float*)d_in[2];
  float* out = (float*)d_out;

  const size_t needA = (size_t)B_ * HP * HP * 128;   // 13,778,944 B
  char* A4 = (char*)d_ws;
  v4i* Wf  = (v4i*)(A4 + needA);                     // 294,912 B
  uint32_t* cnt = (uint32_t*)((char*)Wf + 294912);   // 4 B tile counter

  pack_kernel<<<3441, 256, 0, stream>>>(x, alpha, wt, A4, Wf, cnt);
  conv_mfma_kernel<<<1024, 256, 0, stream>>>(A4, Wf, cnt, out);
}